// Round 2
// baseline (993.760 us; speedup 1.0000x reference)
//
#include <hip/hip_runtime.h>
#include <stdint.h>

// WeightOnlyInt8Linear: out[t,o] = sum_k x[t,k] * (int8 w[o,k] * scale[o]) + bias[o]
// M=8192 tokens, K=4096 in, N=11008 out. fp32 x, int8 weights DELIVERED AS INT32
// by the harness ("integer -> const int*"), fp32 out.
// Strategy: pre-convert x->bf16 and w(int32)->bf16 (exact for [-127,127]) into
// d_ws, then bf16 MFMA GEMM (m97-style 128x128 tile, BK=64, global_load_lds
// staging with pre-swizzled source + XOR-swizzled ds_read_b128).
// Scale+bias applied in fp32 epilogue.

#define TOKENS 8192
#define IN_F   4096
#define OUT_F  11008

#define BM 128
#define BN 128
#define BK 64
#define KT   (IN_F / BK)     // 64 k-tiles
#define MBLK (TOKENS / BM)   // 64
#define NBLK (OUT_F / BN)    // 86
#define NWG  (MBLK * NBLK)   // 5504 (divisible by 8 -> bijective XCD swizzle)

static_assert(NWG % 8 == 0, "XCD swizzle requires nwg % 8 == 0");

typedef __attribute__((ext_vector_type(4))) float f32x4;
typedef __attribute__((ext_vector_type(4))) int   i32x4;
typedef __attribute__((ext_vector_type(4))) unsigned short u16x4;

__device__ __forceinline__ unsigned short f2bf(float f) {
  // round-to-nearest-even fp32 -> bf16 (data has no NaN)
  unsigned int u = __builtin_bit_cast(unsigned int, f);
  u += 0x7FFFu + ((u >> 16) & 1u);
  return (unsigned short)(u >> 16);
}

__device__ __forceinline__ void gload_lds16(const void* g, void* l) {
  // async global->LDS, 16B per lane; LDS dest is wave-uniform base
  // (HW writes lane l at base + l*16). Global src IS per-lane.
  typedef const __attribute__((address_space(1))) unsigned int* gp_t;
  typedef __attribute__((address_space(3))) unsigned int* lp_t;
  __builtin_amdgcn_global_load_lds((gp_t)g, (lp_t)l, 16, 0, 0);
}

// ---------------- convert pass: x fp32 -> bf16 ----------------
__global__ void cvt_x_kernel(const float* __restrict__ x,
                             unsigned short* __restrict__ xb, int n4) {
  int i = blockIdx.x * blockDim.x + threadIdx.x;
  int stride = gridDim.x * blockDim.x;
  for (int v = i; v < n4; v += stride) {
    f32x4 f = ((const f32x4*)x)[v];
    u16x4 r;
#pragma unroll
    for (int j = 0; j < 4; ++j) r[j] = f2bf(f[j]);
    ((u16x4*)xb)[v] = r;
  }
}

// ---------------- convert pass: w int32 (values in [-127,127]) -> bf16 (exact)
__global__ void cvt_w_kernel(const int* __restrict__ w,
                             unsigned short* __restrict__ wb, int n4) {
  int i = blockIdx.x * blockDim.x + threadIdx.x;
  int stride = gridDim.x * blockDim.x;
  for (int c = i; c < n4; c += stride) {
    i32x4 v = ((const i32x4*)w)[c];
    u16x4 r;
#pragma unroll
    for (int j = 0; j < 4; ++j) r[j] = f2bf((float)v[j]);
    ((u16x4*)wb)[c] = r;
  }
}

// ---------------- bf16 MFMA GEMM (NT: A[M][K], B[N][K]) ----------------
// 128x128 tile, BK=64, 4 waves in 2x2 grid, each wave 64x64 out via 4x4
// fragments of mfma_f32_16x16x32_bf16. Single-buffered LDS (m97 structure).
// LDS layout: [128 rows][8 chunks of 16B], chunk XOR-swizzled by (row&7):
// global_load_lds writes linearly, so the SOURCE address is pre-swizzled and
// the ds_read applies the same XOR (both-sides involution, guide rule #21).
__global__ __launch_bounds__(256) void gemm_bf16_kernel(
    const unsigned short* __restrict__ A,   // [TOKENS][IN_F] bf16
    const unsigned short* __restrict__ B,   // [OUT_F][IN_F] bf16
    const float* __restrict__ scale,        // [OUT_F]
    const float* __restrict__ bias,         // [OUT_F]
    float* __restrict__ C)                  // [TOKENS][OUT_F] fp32
{
  __shared__ unsigned short lA[BM * BK];   // 16 KiB
  __shared__ unsigned short lB[BN * BK];   // 16 KiB

  const int tid  = threadIdx.x;
  const int lane = tid & 63;
  const int wave = tid >> 6;   // 0..3
  const int wm   = wave >> 1;  // wave row (2)
  const int wn   = wave & 1;   // wave col (2)

  // XCD-aware swizzle: each XCD gets a contiguous chunk of tile-space.
  int bid = blockIdx.x;
  int wg  = (bid & 7) * (NWG / 8) + (bid >> 3);
  const int m_idx = wg % MBLK;
  const int n_idx = wg / MBLK;
  const int row0 = m_idx * BM;
  const int col0 = n_idx * BN;

  // Staging: 1024 chunks of 16B per tile. Thread covers chunks i*256+wave*64+lane.
  // chunk c -> tile row r=c>>3, slot j=c&7; source slot = j ^ (r&7) (pre-swizzle).
  const unsigned short* aSrc[4];
  const unsigned short* bSrc[4];
  int ldsOff[4];
  char* lAb = (char*)lA;
  char* lBb = (char*)lB;
#pragma unroll
  for (int i = 0; i < 4; ++i) {
    int cbase = i * 256 + wave * 64;   // wave-uniform
    int c = cbase + lane;
    int r = c >> 3, j = c & 7;
    int jg = j ^ (r & 7);
    aSrc[i] = A + (size_t)(row0 + r) * IN_F + (jg << 3);
    bSrc[i] = B + (size_t)(col0 + r) * IN_F + (jg << 3);
    ldsOff[i] = cbase * 16;
  }

  f32x4 zero = {0.f, 0.f, 0.f, 0.f};
  f32x4 acc[4][4];
#pragma unroll
  for (int m = 0; m < 4; ++m)
#pragma unroll
    for (int n = 0; n < 4; ++n) acc[m][n] = zero;

  const int grp  = lane >> 4;   // 0..3 (k-group)
  const int rsel = lane & 15;   // row/col within fragment

  for (int kt = 0; kt < KT; ++kt) {
#pragma unroll
    for (int i = 0; i < 4; ++i)
      gload_lds16(aSrc[i] + kt * BK, lAb + ldsOff[i]);
#pragma unroll
    for (int i = 0; i < 4; ++i)
      gload_lds16(bSrc[i] + kt * BK, lBb + ldsOff[i]);
    __syncthreads();  // drains vmcnt before barrier (compiler-enforced)

#pragma unroll
    for (int kk = 0; kk < 2; ++kk) {
      i32x4 af[4], bf[4];
      const int jw = kk * 4 + grp;
#pragma unroll
      for (int m = 0; m < 4; ++m) {
        int r = wm * 64 + m * 16 + rsel;
        af[m] = *(const i32x4*)(lAb + r * (BK * 2) + ((jw ^ (r & 7)) << 4));
      }
#pragma unroll
      for (int n = 0; n < 4; ++n) {
        int r = wn * 64 + n * 16 + rsel;
        bf[n] = *(const i32x4*)(lBb + r * (BK * 2) + ((jw ^ (r & 7)) << 4));
      }
#pragma unroll
      for (int m = 0; m < 4; ++m)
#pragma unroll
        for (int n = 0; n < 4; ++n)
          asm("v_mfma_f32_16x16x32_bf16 %0, %1, %2, %0"
              : "+v"(acc[m][n])
              : "v"(af[m]), "v"(bf[n]));
    }
    __syncthreads();
  }

  // Inline-asm MFMA bypasses the compiler hazard recognizer: pad the
  // MFMA-write -> VALU-read distance before the epilogue touches acc.
  asm volatile("s_nop 7\n\ts_nop 7" :::);

  // Epilogue: C/D layout col=lane&15, row=(lane>>4)*4+v (m89/m91 verified).
#pragma unroll
  for (int n = 0; n < 4; ++n) {
    int o = col0 + wn * 64 + n * 16 + rsel;
    float s  = scale[o];
    float bz = bias[o];
#pragma unroll
    for (int m = 0; m < 4; ++m) {
      int t = row0 + wm * 64 + m * 16 + grp * 4;
      float* cp = C + (size_t)t * OUT_F + o;
      f32x4 v = acc[m][n];
      cp[0 * (size_t)OUT_F] = v[0] * s + bz;
      cp[1 * (size_t)OUT_F] = v[1] * s + bz;
      cp[2 * (size_t)OUT_F] = v[2] * s + bz;
      cp[3 * (size_t)OUT_F] = v[3] * s + bz;
    }
  }
}

// ---------------- fallback (only if ws too small): naive fp32 ----------------
__global__ void gemm_naive_kernel(const float* __restrict__ x,
                                  const int* __restrict__ w,
                                  const float* __restrict__ sc,
                                  const float* __restrict__ bs,
                                  float* __restrict__ out) {
  long long idx = (long long)blockIdx.x * blockDim.x + threadIdx.x;
  long long total = (long long)TOKENS * OUT_F;
  if (idx >= total) return;
  int t = (int)(idx / OUT_F);
  int o = (int)(idx % OUT_F);
  const float* xp = x + (size_t)t * IN_F;
  const int* wp = w + (size_t)o * IN_F;
  float acc = 0.f;
  for (int k = 0; k < IN_F; k += 4) {
    i32x4 wv = *(const i32x4*)(wp + k);
    f32x4 xv = *(const f32x4*)(xp + k);
    acc += xv[0] * (float)wv[0] + xv[1] * (float)wv[1]
         + xv[2] * (float)wv[2] + xv[3] * (float)wv[3];
  }
  out[idx] = acc * sc[o] + bs[o];
}

extern "C" void kernel_launch(void* const* d_in, const int* in_sizes, int n_in,
                              void* d_out, int out_size, void* d_ws, size_t ws_size,
                              hipStream_t stream) {
  const float* x  = (const float*)d_in[0];
  const int*   qw = (const int*)d_in[1];     // int8 values materialized as int32
  const float* sc = (const float*)d_in[2];
  const float* bs = (const float*)d_in[3];
  float* out = (float*)d_out;

  const size_t xbBytes = (size_t)TOKENS * IN_F * sizeof(unsigned short); // 64 MiB
  const size_t wbBytes = (size_t)OUT_F * IN_F * sizeof(unsigned short);  // 86 MiB

  if (ws_size >= xbBytes + wbBytes) {
    unsigned short* xb = (unsigned short*)d_ws;
    unsigned short* wb = (unsigned short*)((char*)d_ws + xbBytes);
    cvt_x_kernel<<<2048, 256, 0, stream>>>(x, xb, TOKENS * IN_F / 4);
    cvt_w_kernel<<<2048, 256, 0, stream>>>(qw, wb, OUT_F * IN_F / 4);
    gemm_bf16_kernel<<<NWG, 256, 0, stream>>>(xb, wb, sc, bs, out);
  } else {
    long long total = (long long)TOKENS * OUT_F;
    int blocks = (int)((total + 255) / 256);
    gemm_naive_kernel<<<blocks, 256, 0, stream>>>(x, qw, sc, bs, out);
  }
}

// Round 3
// 846.137 us; speedup vs baseline: 1.1745x; 1.1745x over previous
//
#include <hip/hip_runtime.h>
#include <stdint.h>

// WeightOnlyInt8Linear: out[t,o] = sum_k x[t,k] * (int8 w[o,k] * scale[o]) + bias[o]
// M=8192, K=4096, N=11008. x fp32, w int8-as-int32 (harness), out fp32.
// Round 2: 256x256 tile, BK=64, 8 waves (2x4), double-buffered 128 KiB LDS,
// counted vmcnt(8) at K-tile boundaries (loads stay in flight across barriers),
// raw s_barrier (no vmcnt(0) drain), setprio around MFMA clusters,
// both-sides XOR swizzle (verified: bank conflicts == 0 in round 1),
// XCD-aware bijective block swizzle (NWG=1376 % 8 == 0).

#define TOKENS 8192
#define IN_F   4096
#define OUT_F  11008

#define BM 256
#define BN 256
#define BK 64
#define KT   (IN_F / BK)     // 64 k-tiles
#define MBLK (TOKENS / BM)   // 32
#define NBLK (OUT_F / BN)    // 43
#define NWG  (MBLK * NBLK)   // 1376

static_assert(NWG % 8 == 0, "XCD swizzle requires nwg % 8 == 0");

#define LDS_BUF   65536      // A(32K) + B(32K) per buffer
#define LDS_BREG  32768      // B region offset within buffer
#define LDS_TOTAL 131072     // 2 buffers

typedef __attribute__((ext_vector_type(4))) float f32x4;
typedef __attribute__((ext_vector_type(4))) int   i32x4;
typedef __attribute__((ext_vector_type(4))) unsigned short u16x4;

__device__ __forceinline__ unsigned short f2bf(float f) {
  unsigned int u = __builtin_bit_cast(unsigned int, f);
  u += 0x7FFFu + ((u >> 16) & 1u);
  return (unsigned short)(u >> 16);
}

__device__ __forceinline__ void gload_lds16(const void* g, void* l) {
  typedef const __attribute__((address_space(1))) unsigned int* gp_t;
  typedef __attribute__((address_space(3))) unsigned int* lp_t;
  __builtin_amdgcn_global_load_lds((gp_t)g, (lp_t)l, 16, 0, 0);
}

#define MFMA(d, a, b) \
  asm("v_mfma_f32_16x16x32_bf16 %0, %1, %2, %0" : "+v"(d) : "v"(a), "v"(b))

// ---------------- convert pass: x fp32 -> bf16 ----------------
__global__ void cvt_x_kernel(const float* __restrict__ x,
                             unsigned short* __restrict__ xb, int n4) {
  int i = blockIdx.x * blockDim.x + threadIdx.x;
  int stride = gridDim.x * blockDim.x;
  for (int v = i; v < n4; v += stride) {
    f32x4 f = ((const f32x4*)x)[v];
    u16x4 r;
#pragma unroll
    for (int j = 0; j < 4; ++j) r[j] = f2bf(f[j]);
    ((u16x4*)xb)[v] = r;
  }
}

// ---------------- convert pass: w int32 in [-127,127] -> bf16 (exact) -------
__global__ void cvt_w_kernel(const int* __restrict__ w,
                             unsigned short* __restrict__ wb, int n4) {
  int i = blockIdx.x * blockDim.x + threadIdx.x;
  int stride = gridDim.x * blockDim.x;
  for (int c = i; c < n4; c += stride) {
    i32x4 v = ((const i32x4*)w)[c];
    u16x4 r;
#pragma unroll
    for (int j = 0; j < 4; ++j) r[j] = f2bf((float)v[j]);
    ((u16x4*)wb)[c] = r;
  }
}

// ---------------- bf16 MFMA GEMM, 256x256 tile, deep pipeline ----------------
__global__ __launch_bounds__(512) void gemm_bf16_kernel(
    const unsigned short* __restrict__ A,   // [TOKENS][IN_F] bf16
    const unsigned short* __restrict__ B,   // [OUT_F][IN_F] bf16
    const float* __restrict__ scale,        // [OUT_F]
    const float* __restrict__ bias,         // [OUT_F]
    float* __restrict__ C)                  // [TOKENS][OUT_F] fp32
{
  extern __shared__ char lds[];            // 128 KiB: [2][A 32K | B 32K]

  const int tid  = threadIdx.x;
  const int lane = tid & 63;
  const int wave = tid >> 6;   // 0..7
  const int wm   = wave >> 2;  // 0..1  (128-row half)
  const int wn   = wave & 3;   // 0..3  (64-col quarter)
  const int grp  = lane >> 4;  // 0..3
  const int rsel = lane & 15;  // 0..15

  // XCD-aware bijective swizzle
  int bid = blockIdx.x;
  int wg  = (bid & 7) * (NWG / 8) + (bid >> 3);
  const int m_idx = wg % MBLK;
  const int n_idx = wg / MBLK;
  const int row0 = m_idx * BM;
  const int col0 = n_idx * BN;

  // Staging: per operand 2048 chunks of 16B; thread covers c = i*512 + tid.
  // chunk c -> row r=c>>3, slot j=c&7; pre-swizzled source slot jg=j^(r&7).
  const unsigned short* aSrc[4];
  const unsigned short* bSrc[4];
  int ldsOff[4];
#pragma unroll
  for (int i = 0; i < 4; ++i) {
    int cb = i * 512 + wave * 64;   // wave-uniform
    int ci = cb + lane;
    int r = ci >> 3, j = ci & 7;
    int jg = j ^ (r & 7);
    aSrc[i] = A + (size_t)(row0 + r) * IN_F + (jg << 3);
    bSrc[i] = B + (size_t)(col0 + r) * IN_F + (jg << 3);
    ldsOff[i] = cb * 16;
  }

  auto stage = [&](int tt) {  // issue 8 global_load_lds for K-tile tt
    char* base = lds + (tt & 1) * LDS_BUF;
#pragma unroll
    for (int i = 0; i < 4; ++i)
      gload_lds16(aSrc[i] + tt * BK, base + ldsOff[i]);
#pragma unroll
    for (int i = 0; i < 4; ++i)
      gload_lds16(bSrc[i] + tt * BK, base + LDS_BREG + ldsOff[i]);
  };

  f32x4 zero = {0.f, 0.f, 0.f, 0.f};
  f32x4 acc[8][4];
#pragma unroll
  for (int m = 0; m < 8; ++m)
#pragma unroll
    for (int n = 0; n < 4; ++n) acc[m][n] = zero;

  // fragment loads from swizzled LDS (row stride 128B, chunk jw=kk*4+grp)
  auto ldA = [&](const char* bufA, int m, int kk) -> i32x4 {
    int r = wm * 128 + m * 16 + rsel;
    int jw = kk * 4 + grp;
    return *(const i32x4*)(bufA + r * (BK * 2) + ((jw ^ (r & 7)) << 4));
  };
  auto ldB = [&](const char* bufB, int n, int kk) -> i32x4 {
    int r = wn * 64 + n * 16 + rsel;
    int jw = kk * 4 + grp;
    return *(const i32x4*)(bufB + r * (BK * 2) + ((jw ^ (r & 7)) << 4));
  };

  // Prologue: tiles 0 and 1 in flight; wait for tile 0 only (counted).
  stage(0);
  stage(1);
  asm volatile("s_waitcnt vmcnt(8)" ::: "memory");
  __builtin_amdgcn_s_barrier();

  for (int t = 0; t < KT; ++t) {
    const char* bufA = lds + (t & 1) * LDS_BUF;
    const char* bufB = bufA + LDS_BREG;

    i32x4 af[8], bfr[4];

    // ---- phase 0: quadrant (m 0-3) x (n 0-1) ----
#pragma unroll
    for (int m = 0; m < 4; ++m) {
      af[2 * m]     = ldA(bufA, m, 0);
      af[2 * m + 1] = ldA(bufA, m, 1);
    }
#pragma unroll
    for (int n = 0; n < 2; ++n) {
      bfr[2 * n]     = ldB(bufB, n, 0);
      bfr[2 * n + 1] = ldB(bufB, n, 1);
    }
    __builtin_amdgcn_s_setprio(1);
#pragma unroll
    for (int m = 0; m < 4; ++m)
#pragma unroll
      for (int n = 0; n < 2; ++n)
#pragma unroll
        for (int kk = 0; kk < 2; ++kk)
          MFMA(acc[m][n], af[2 * m + kk], bfr[2 * n + kk]);
    __builtin_amdgcn_s_setprio(0);

    // ---- phase 1: (m 0-3) x (n 2-3), A kept in regs ----
#pragma unroll
    for (int n = 2; n < 4; ++n) {
      bfr[2 * (n - 2)]     = ldB(bufB, n, 0);
      bfr[2 * (n - 2) + 1] = ldB(bufB, n, 1);
    }
    __builtin_amdgcn_s_setprio(1);
#pragma unroll
    for (int m = 0; m < 4; ++m)
#pragma unroll
      for (int n = 2; n < 4; ++n)
#pragma unroll
        for (int kk = 0; kk < 2; ++kk)
          MFMA(acc[m][n], af[2 * m + kk], bfr[2 * (n - 2) + kk]);
    __builtin_amdgcn_s_setprio(0);

    // ---- phase 2: (m 4-7) x (n 2-3), B kept in regs ----
#pragma unroll
    for (int m = 4; m < 8; ++m) {
      af[2 * (m - 4)]     = ldA(bufA, m, 0);
      af[2 * (m - 4) + 1] = ldA(bufA, m, 1);
    }
    __builtin_amdgcn_s_setprio(1);
#pragma unroll
    for (int m = 4; m < 8; ++m)
#pragma unroll
      for (int n = 2; n < 4; ++n)
#pragma unroll
        for (int kk = 0; kk < 2; ++kk)
          MFMA(acc[m][n], af[2 * (m - 4) + kk], bfr[2 * (n - 2) + kk]);
    __builtin_amdgcn_s_setprio(0);

    // ---- phase 3: (m 4-7) x (n 0-1), A kept in regs ----
#pragma unroll
    for (int n = 0; n < 2; ++n) {
      bfr[2 * n]     = ldB(bufB, n, 0);
      bfr[2 * n + 1] = ldB(bufB, n, 1);
    }
    __builtin_amdgcn_s_setprio(1);
#pragma unroll
    for (int m = 4; m < 8; ++m)
#pragma unroll
      for (int n = 0; n < 2; ++n)
#pragma unroll
        for (int kk = 0; kk < 2; ++kk)
          MFMA(acc[m][n], af[2 * (m - 4) + kk], bfr[2 * n + kk]);
    __builtin_amdgcn_s_setprio(0);

    // ---- K-tile boundary: counted-vmcnt pipeline ----
    if (t + 1 < KT) {
      // all our ds_reads of buf[t&1] retired before anyone overwrites it
      asm volatile("s_waitcnt lgkmcnt(0)" ::: "memory");
      __builtin_amdgcn_s_barrier();
      if (t + 2 < KT) {
        stage(t + 2);   // into buf[t&1], just freed
        asm volatile("s_waitcnt vmcnt(8)" ::: "memory");  // t+1 landed; t+2 in flight
      } else {
        asm volatile("s_waitcnt vmcnt(0)" ::: "memory");  // drain only at the tail
      }
      __builtin_amdgcn_s_barrier();
    }
  }

  // inline-asm MFMA bypasses hazard recognizer: pad before VALU reads acc
  asm volatile("s_nop 7\n\ts_nop 7" :::);

  // Epilogue: C/D layout col=lane&15, row=(lane>>4)*4+v
#pragma unroll
  for (int n = 0; n < 4; ++n) {
    int o = col0 + wn * 64 + n * 16 + rsel;
    float s  = scale[o];
    float bz = bias[o];
#pragma unroll
    for (int m = 0; m < 8; ++m) {
      int tr = row0 + wm * 128 + m * 16 + grp * 4;
      float* cp = C + (size_t)tr * OUT_F + o;
      f32x4 v = acc[m][n];
      cp[0 * (size_t)OUT_F] = v[0] * s + bz;
      cp[1 * (size_t)OUT_F] = v[1] * s + bz;
      cp[2 * (size_t)OUT_F] = v[2] * s + bz;
      cp[3 * (size_t)OUT_F] = v[3] * s + bz;
    }
  }
}

// ---------------- fallback (only if ws too small): naive fp32 ----------------
__global__ void gemm_naive_kernel(const float* __restrict__ x,
                                  const int* __restrict__ w,
                                  const float* __restrict__ sc,
                                  const float* __restrict__ bs,
                                  float* __restrict__ out) {
  long long idx = (long long)blockIdx.x * blockDim.x + threadIdx.x;
  long long total = (long long)TOKENS * OUT_F;
  if (idx >= total) return;
  int t = (int)(idx / OUT_F);
  int o = (int)(idx % OUT_F);
  const float* xp = x + (size_t)t * IN_F;
  const int* wp = w + (size_t)o * IN_F;
  float acc = 0.f;
  for (int k = 0; k < IN_F; k += 4) {
    i32x4 wv = *(const i32x4*)(wp + k);
    f32x4 xv = *(const f32x4*)(xp + k);
    acc += xv[0] * (float)wv[0] + xv[1] * (float)wv[1]
         + xv[2] * (float)wv[2] + xv[3] * (float)wv[3];
  }
  out[idx] = acc * sc[o] + bs[o];
}

extern "C" void kernel_launch(void* const* d_in, const int* in_sizes, int n_in,
                              void* d_out, int out_size, void* d_ws, size_t ws_size,
                              hipStream_t stream) {
  const float* x  = (const float*)d_in[0];
  const int*   qw = (const int*)d_in[1];     // int8 values materialized as int32
  const float* sc = (const float*)d_in[2];
  const float* bs = (const float*)d_in[3];
  float* out = (float*)d_out;

  const size_t xbBytes = (size_t)TOKENS * IN_F * sizeof(unsigned short); // 64 MiB
  const size_t wbBytes = (size_t)OUT_F * IN_F * sizeof(unsigned short);  // 86 MiB

  if (ws_size >= xbBytes + wbBytes) {
    unsigned short* xb = (unsigned short*)d_ws;
    unsigned short* wb = (unsigned short*)((char*)d_ws + xbBytes);
    cvt_x_kernel<<<2048, 256, 0, stream>>>(x, xb, TOKENS * IN_F / 4);
    cvt_w_kernel<<<2048, 256, 0, stream>>>(qw, wb, OUT_F * IN_F / 4);
    // 128 KiB dynamic LDS (> 64 KiB default cap)
    (void)hipFuncSetAttribute((const void*)gemm_bf16_kernel,
                              hipFuncAttributeMaxDynamicSharedMemorySize,
                              LDS_TOTAL);
    gemm_bf16_kernel<<<NWG, 512, LDS_TOTAL, stream>>>(xb, wb, sc, bs, out);
  } else {
    long long total = (long long)TOKENS * OUT_F;
    int blocks = (int)((total + 255) / 256);
    gemm_naive_kernel<<<blocks, 256, 0, stream>>>(x, qw, sc, bs, out);
  }
}